// Round 2
// 437.352 us; speedup vs baseline: 1.0748x; 1.0748x over previous
//
#include <hip/hip_runtime.h>

#define DIN 55
#define HD 128
#define EB 8192          // edges per partition block
#define NBKT 512         // radix buckets (dst >> 8)

typedef unsigned short u16;
typedef unsigned int u32;
typedef short short8 __attribute__((ext_vector_type(8)));
typedef _Float16 h8 __attribute__((ext_vector_type(8)));
typedef _Float16 h2 __attribute__((ext_vector_type(2)));
typedef float f32x4 __attribute__((ext_vector_type(4)));

// ---- fp16 helpers ----
// pack two f32 -> packed f16 pair (single v_cvt_pkrtz_f16_f32)
__device__ __forceinline__ u32 pkh(float a, float b) {
    auto r = __builtin_amdgcn_cvt_pkrtz(a, b);
    union { decltype(r) h; u32 u; } c; c.h = r; return c.u;
}
__device__ __forceinline__ float hLo(u32 u) {
    union { u16 s; _Float16 f; } c; c.s = (u16)u; return (float)c.f;
}
__device__ __forceinline__ float hHi(u32 u) {
    union { u16 s; _Float16 f; } c; c.s = (u16)(u >> 16); return (float)c.f;
}

// ---------------- utility ----------------
__global__ void zero_f32_kernel(float* p, int n) {
    int i = blockIdx.x * blockDim.x + threadIdx.x;
    if (i < n) p[i] = 0.f;
}

// ---------------- hierarchical inclusive scan (for histT only) ----------------
__global__ __launch_bounds__(256) void scan1_kernel(int* data, int* bsums, int n) {
    __shared__ int sT[256];
    int t = threadIdx.x;
    int base = blockIdx.x * 1024 + t * 4;
    int v0 = (base + 0 < n) ? data[base + 0] : 0;
    int v1 = (base + 1 < n) ? data[base + 1] : 0;
    int v2 = (base + 2 < n) ? data[base + 2] : 0;
    int v3 = (base + 3 < n) ? data[base + 3] : 0;
    v1 += v0; v2 += v1; v3 += v2;
    sT[t] = v3;
    __syncthreads();
    for (int off = 1; off < 256; off <<= 1) {
        int x = (t >= off) ? sT[t - off] : 0;
        __syncthreads();
        sT[t] += x;
        __syncthreads();
    }
    int excl = (t == 0) ? 0 : sT[t - 1];
    if (base + 0 < n) data[base + 0] = v0 + excl;
    if (base + 1 < n) data[base + 1] = v1 + excl;
    if (base + 2 < n) data[base + 2] = v2 + excl;
    if (base + 3 < n) data[base + 3] = v3 + excl;
    if (t == 255) bsums[blockIdx.x] = sT[255];
}
__global__ __launch_bounds__(1024) void scan2_kernel(int* bsums, int nb) {
    __shared__ int s[1024];
    int t = threadIdx.x;
    int v = (t < nb) ? bsums[t] : 0;
    s[t] = v;
    __syncthreads();
    for (int o = 1; o < 1024; o <<= 1) {
        int x = (t >= o) ? s[t - o] : 0;
        __syncthreads();
        s[t] += x;
        __syncthreads();
    }
    if (t < nb) bsums[t] = s[t] - v;   // exclusive
}
__global__ void scan3_kernel(int* data, const int* __restrict__ bsums, int n) {
    int i = blockIdx.x * blockDim.x + threadIdx.x;
    if (i < n) data[i] += bsums[i >> 10];
}

// ---------------- radix partition of edges by dst>>8 ----------------
__global__ __launch_bounds__(256) void rhist_kernel(const int* __restrict__ dst,
                                                    int* __restrict__ histT, int E, int nB) {
    __shared__ int hh[NBKT];
    int t = threadIdx.x;
    for (int i = t; i < NBKT; i += 256) hh[i] = 0;
    __syncthreads();
    int base = blockIdx.x * EB;
    int end = min(base + EB, E);
    for (int i = base + t; i < end; i += 256) atomicAdd(&hh[dst[i] >> 8], 1);
    __syncthreads();
    for (int b = t; b < NBKT; b += 256) histT[b * nB + blockIdx.x] = hh[b];
}

// ticket from scanned histT directly (exclusive base = scanned[flat-1]); LDS atomics only
__global__ __launch_bounds__(256) void rpos_kernel(const int* __restrict__ src,
                                                   const int* __restrict__ dst,
                                                   const int* __restrict__ scanned,
                                                   u32* __restrict__ bpairs, int E, int nB) {
    __shared__ int cur[NBKT];
    int t = threadIdx.x;
    for (int b = t; b < NBKT; b += 256) {
        int idx = b * nB + blockIdx.x;
        cur[b] = (idx == 0) ? 0 : scanned[idx - 1];
    }
    __syncthreads();
    int base = blockIdx.x * EB;
    int end = min(base + EB, E);
    for (int i = base + t; i < end; i += 256) {
        int d = dst[i];
        int p = atomicAdd(&cur[d >> 8], 1);
        bpairs[p] = ((u32)src[i] << 8) | (u32)(d & 255);
    }
}

// fused per-bucket: count -> local scan -> write off -> scatter esrc (all LDS)
__global__ __launch_bounds__(256) void bfinal_kernel(const u32* __restrict__ bpairs,
                                                     const int* __restrict__ scanned,
                                                     int* __restrict__ off,
                                                     int* __restrict__ esrc, int N, int nB) {
    __shared__ int cnt[256];
    __shared__ int sc[256];
    __shared__ int cur[256];
    int b = blockIdx.x, t = threadIdx.x;
    int lo = (b == 0) ? 0 : scanned[b * nB - 1];
    int hi = scanned[(b + 1) * nB - 1];
    cnt[t] = 0;
    __syncthreads();
    for (int i = lo + t; i < hi; i += 256) atomicAdd(&cnt[bpairs[i] & 255u], 1);
    __syncthreads();
    int v = cnt[t];
    sc[t] = v;
    __syncthreads();
    for (int o = 1; o < 256; o <<= 1) {
        int x = (t >= o) ? sc[t - o] : 0;
        __syncthreads();
        sc[t] += x;
        __syncthreads();
    }
    int incl = sc[t];
    int gbase = lo + incl - v;
    int n = b * 256 + t;
    if (n < N) off[n] = gbase;
    if (n == N - 1) off[N] = lo + incl;
    cur[t] = gbase;
    __syncthreads();
    for (int i = lo + t; i < hi; i += 256) {
        u32 p = bpairs[i];
        int q = atomicAdd(&cur[p & 255u], 1);
        esrc[q] = (int)(p >> 8);
    }
}

// ---------------- node projection: h = x @ W_fc + b_fc  (fp32 math, f16 out) ----------------
__global__ __launch_bounds__(512, 2) void fc_kernel(const float* __restrict__ x,
                                                    const float* __restrict__ Wfc,
                                                    const float* __restrict__ bfc,
                                                    u16* __restrict__ h,
                                                    int N, int nTiles) {
    __shared__ float sW[DIN * HD];
    __shared__ float sX[128 * 56];
    for (int i = threadIdx.x; i < DIN * HD / 4; i += 512)
        ((float4*)sW)[i] = ((const float4*)Wfc)[i];
    const int c = threadIdx.x & 15;
    const int r = threadIdx.x >> 4;
    float4 bb0 = ((const float4*)bfc)[2 * c];
    float4 bb1 = ((const float4*)bfc)[2 * c + 1];

    for (int tile = blockIdx.x; tile < nTiles; tile += gridDim.x) {
        int base = tile * 128;
        int limit = min(128, N - base) * DIN;
        __syncthreads();
        for (int i = threadIdx.x; i < 128 * DIN; i += 512) {
            float v = (i < limit) ? x[(size_t)base * DIN + i] : 0.f;
            sX[(i / DIN) * 56 + (i % DIN)] = v;
        }
        __syncthreads();

        float acc[4][8];
#pragma unroll
        for (int ii = 0; ii < 4; ii++) {
            acc[ii][0] = bb0.x; acc[ii][1] = bb0.y; acc[ii][2] = bb0.z; acc[ii][3] = bb0.w;
            acc[ii][4] = bb1.x; acc[ii][5] = bb1.y; acc[ii][6] = bb1.z; acc[ii][7] = bb1.w;
        }
        const int n0 = r * 4;
#pragma unroll 5
        for (int k = 0; k < DIN; k++) {
            float4 w0 = *(const float4*)&sW[k * HD + c * 8];
            float4 w1 = *(const float4*)&sW[k * HD + c * 8 + 4];
            float av[4] = {sX[(n0 + 0) * 56 + k], sX[(n0 + 1) * 56 + k],
                           sX[(n0 + 2) * 56 + k], sX[(n0 + 3) * 56 + k]};
#pragma unroll
            for (int ii = 0; ii < 4; ii++) {
                acc[ii][0] += av[ii] * w0.x; acc[ii][1] += av[ii] * w0.y;
                acc[ii][2] += av[ii] * w0.z; acc[ii][3] += av[ii] * w0.w;
                acc[ii][4] += av[ii] * w1.x; acc[ii][5] += av[ii] * w1.y;
                acc[ii][6] += av[ii] * w1.z; acc[ii][7] += av[ii] * w1.w;
            }
        }
        int nvalid = N - base;
#pragma unroll
        for (int ii = 0; ii < 4; ii++) {
            if (n0 + ii < nvalid) {
                u32 p0 = pkh(acc[ii][0], acc[ii][1]);
                u32 p1 = pkh(acc[ii][2], acc[ii][3]);
                u32 p2 = pkh(acc[ii][4], acc[ii][5]);
                u32 p3 = pkh(acc[ii][6], acc[ii][7]);
                *(uint4*)&h[(size_t)(base + n0 + ii) * HD + c * 8] = make_uint4(p0, p1, p2, p3);
            }
        }
    }
}

// ---------------- edge aggregation: z[n] = h[n] + sum_{e} h[esrc[e]]  (f16, packed adds) ----------------
// one wave per node — maximal wave count for latency hiding (R10 showed fusing this kills it).
// fp16 lets the accumulate run as v_pk_add_f16 directly on gathered vectors: 4 VALU ops per
// 16B vector instead of 16 (8 unpack + 8 f32 add) — VALU no longer competes with the gather.
__global__ __launch_bounds__(256) void agg_kernel(const u16* __restrict__ h,
                                                  const int* __restrict__ off,
                                                  const int* __restrict__ esrc,
                                                  u16* __restrict__ z, int N) {
    int w = threadIdx.x >> 6, lane = threadIdx.x & 63;
    int n = blockIdx.x * 4 + w;
    if (n >= N) return;
    int s0 = off[n], s1 = off[n + 1];
    int g = lane >> 4, q = lane & 15;
    h8 acc = {0, 0, 0, 0, 0, 0, 0, 0};
    int t = s0;
#define ACCV(E) acc += *(const h8*)&h[(size_t)(E) * HD + q * 8];
    for (; t + 16 <= s1; t += 16) {
        int e0 = esrc[t + g], e1 = esrc[t + 4 + g];
        int e2 = esrc[t + 8 + g], e3 = esrc[t + 12 + g];
        ACCV(e0); ACCV(e1); ACCV(e2); ACCV(e3);
    }
    for (; t + 4 <= s1; t += 4) {
        int e0 = esrc[t + g];
        ACCV(e0);
    }
    if (t + g < s1) {
        int e0 = esrc[t + g];
        ACCV(e0);
    }
    if (g == 0) {
        ACCV(n);           // self term: (1+eps)*h with eps=0
    }
#undef ACCV
    union { h8 v; uint4 u; } A; A.v = acc;
    {
        union { uint4 u; h8 v; } B;
        B.u.x = __shfl_down(A.u.x, 32); B.u.y = __shfl_down(A.u.y, 32);
        B.u.z = __shfl_down(A.u.z, 32); B.u.w = __shfl_down(A.u.w, 32);
        A.v += B.v;
        B.u.x = __shfl_down(A.u.x, 16); B.u.y = __shfl_down(A.u.y, 16);
        B.u.z = __shfl_down(A.u.z, 16); B.u.w = __shfl_down(A.u.w, 16);
        A.v += B.v;
    }
    if (g == 0) {
        *(uint4*)&z[(size_t)n * HD + q * 8] = A.u;
    }
}

// ---------------- fused MLP pair (R8 structure, f16 MFMA): ----------------
// Transposed GEMMs (A = weights, B = activations). Coalesced prefetch staging through sA,
// z1 via b64 row-major LDS, GEMM2 B-frags contiguous b128, coalesced epilogue through sZ.
__global__ __launch_bounds__(512, 2) void mlp_pair_kernel(const u16* __restrict__ in,
                                                          const float* __restrict__ W1,
                                                          const float* __restrict__ b1,
                                                          const float* __restrict__ W2,
                                                          const float* __restrict__ b2,
                                                          u16* __restrict__ out,
                                                          int N, int nTiles) {
    __shared__ u16 sB1[16384];           // W1 frags: [ft][kc][slot][8]
    __shared__ u16 sB2[16384];           // W2 frags
    __shared__ u16 sA[16384];            // activation frags: [nt][kc][slot][8]
    __shared__ u16 sZ[128 * 136];        // row-major activations [node][feature], pad 136

    const int t = threadIdx.x;
    // --- build weight frags (stage fp32->f16 rows into sZ scratch, then fragment) ---
    for (int wsel = 0; wsel < 2; wsel++) {
        const float* W = wsel ? W2 : W1;
        u16* sB = wsel ? sB2 : sB1;
        __syncthreads();
        for (int c = t; c < 128 * 32; c += 512) {
            int k = c >> 5, j4 = c & 31;
            float4 wv = ((const float4*)W)[c];
            u32 p0 = pkh(wv.x, wv.y);
            u32 p1 = pkh(wv.z, wv.w);
            *(uint2*)&sZ[k * 136 + j4 * 4] = make_uint2(p0, p1);
        }
        __syncthreads();
        for (int e = t; e < 2048; e += 512) {
            int L = e & 63, gq = e >> 6;
            int ct = gq >> 2, kc = gq & 3;
            int j = ct * 16 + (L & 15);
            int k0 = kc * 32 + ((L >> 4) << 3);
            short8 sv;
#pragma unroll
            for (int i = 0; i < 8; i++) sv[i] = (short)sZ[(k0 + i) * 136 + j];
            int slot = L ^ (kc << 1);
            *(short8*)&sB[(((ct << 2) + kc) << 6 | slot) * 8] = sv;
        }
    }

    const int w = t >> 6, lane = t & 63;
    const int col = lane & 15;           // node within tile
    const int fq = lane >> 4;            // feature quad
    const int fbase = (w & 3) << 5;      // wave's 32 features (2 f-tiles)
    const int nbase = (w >> 2) << 6;     // wave's 64 nodes (4 n-tiles)
    float4 bias1v[2], bias2v[2];
#pragma unroll
    for (int ftl = 0; ftl < 2; ftl++) {
        bias1v[ftl] = *(const float4*)&b1[fbase + ftl * 16 + fq * 4];
        bias2v[ftl] = *(const float4*)&b2[fbase + ftl * 16 + fq * 4];
    }

    // prefetch tile 0
    uint4 pf[4];
    int tile = blockIdx.x;
    if (tile < nTiles) {
        int base = tile * 128;
        int limit = min(128, N - base) * 16;
#pragma unroll
        for (int i = 0; i < 4; i++) {
            int c = t + 512 * i;
            uint4 raw = make_uint4(0, 0, 0, 0);
            if (c < limit)
                raw = *(const uint4*)&in[((size_t)(base + (c >> 4))) * HD + (c & 15) * 8];
            pf[i] = raw;
        }
    }

    for (; tile < nTiles; tile += gridDim.x) {
        int base = tile * 128;
        int nvalid = N - base;
        __syncthreads();                 // S1: prev tile fully done (sA & sZ free)
#pragma unroll
        for (int i = 0; i < 4; i++) {    // regs -> sA (swizzled fragment slots)
            int c = t + 512 * i;
            int n = c >> 4, k8 = c & 15;
            int nt = n >> 4, kc = k8 >> 2;
            int L = ((k8 & 3) << 4) | (n & 15);
            int slot = L ^ (kc << 1);
            *(uint4*)&sA[(((nt << 2) + kc) << 6 | slot) * 8] = pf[i];
        }
        __syncthreads();                 // S2

        // issue next tile's prefetch (overlaps with both GEMMs)
        int ntile = tile + gridDim.x;
        if (ntile < nTiles) {
            int nb2 = ntile * 128;
            int nlimit = min(128, N - nb2) * 16;
#pragma unroll
            for (int i = 0; i < 4; i++) {
                int c = t + 512 * i;
                uint4 raw = make_uint4(0, 0, 0, 0);
                if (c < nlimit)
                    raw = *(const uint4*)&in[((size_t)(nb2 + (c >> 4))) * HD + (c & 15) * 8];
                pf[i] = raw;
            }
        }

        // --- GEMM1: D[feature][node] = W1^T (A) x in^T (B) ---
        h8 aw1[2][4];
#pragma unroll
        for (int ftl = 0; ftl < 2; ftl++) {
            int ft = ((w & 3) << 1) + ftl;
#pragma unroll
            for (int kc = 0; kc < 4; kc++)
                aw1[ftl][kc] = *(const h8*)&sB1[(((ft << 2) + kc) << 6 | (lane ^ (kc << 1))) * 8];
        }
        h8 bx[4][4];
#pragma unroll
        for (int ntl = 0; ntl < 4; ntl++) {
            int nt = ((w >> 2) << 2) + ntl;
#pragma unroll
            for (int kc = 0; kc < 4; kc++)
                bx[ntl][kc] = *(const h8*)&sA[(((nt << 2) + kc) << 6 | (lane ^ (kc << 1))) * 8];
        }
        f32x4 acc1[2][4];
#pragma unroll
        for (int ftl = 0; ftl < 2; ftl++)
#pragma unroll
            for (int ntl = 0; ntl < 4; ntl++) {
                acc1[ftl][ntl][0] = bias1v[ftl].x; acc1[ftl][ntl][1] = bias1v[ftl].y;
                acc1[ftl][ntl][2] = bias1v[ftl].z; acc1[ftl][ntl][3] = bias1v[ftl].w;
            }
#pragma unroll
        for (int ntl = 0; ntl < 4; ntl++)
#pragma unroll
            for (int kc = 0; kc < 4; kc++) {
                acc1[0][ntl] = __builtin_amdgcn_mfma_f32_16x16x32_f16(aw1[0][kc], bx[ntl][kc], acc1[0][ntl], 0, 0, 0);
                acc1[1][ntl] = __builtin_amdgcn_mfma_f32_16x16x32_f16(aw1[1][kc], bx[ntl][kc], acc1[1][ntl], 0, 0, 0);
            }
        // --- write z1 = relu(acc1) row-major into sZ via b64 (4 consecutive features) ---
#pragma unroll
        for (int ftl = 0; ftl < 2; ftl++) {
            int f = fbase + ftl * 16 + fq * 4;
#pragma unroll
            for (int ntl = 0; ntl < 4; ntl++) {
                int n = nbase + ntl * 16 + col;
                float v0 = fmaxf(acc1[ftl][ntl][0], 0.f);
                float v1 = fmaxf(acc1[ftl][ntl][1], 0.f);
                float v2 = fmaxf(acc1[ftl][ntl][2], 0.f);
                float v3 = fmaxf(acc1[ftl][ntl][3], 0.f);
                u32 lo = pkh(v0, v1);
                u32 hi = pkh(v2, v3);
                *(uint2*)&sZ[n * 136 + f] = make_uint2(lo, hi);
            }
        }
        __syncthreads();                 // S3: z1 ready
        // --- GEMM2: D[feature][node] = W2^T (A) x z1^T (B); B-frags contiguous b128 ---
        h8 aw2[2][4];
#pragma unroll
        for (int ftl = 0; ftl < 2; ftl++) {
            int ft = ((w & 3) << 1) + ftl;
#pragma unroll
            for (int kc = 0; kc < 4; kc++)
                aw2[ftl][kc] = *(const h8*)&sB2[(((ft << 2) + kc) << 6 | (lane ^ (kc << 1))) * 8];
        }
        h8 bz[4][4];
#pragma unroll
        for (int ntl = 0; ntl < 4; ntl++) {
            int n = nbase + ntl * 16 + col;
#pragma unroll
            for (int kc = 0; kc < 4; kc++) {
                int k0 = kc * 32 + fq * 8;
                bz[ntl][kc] = *(const h8*)&sZ[n * 136 + k0];
            }
        }
        f32x4 acc2[2][4];
#pragma unroll
        for (int ftl = 0; ftl < 2; ftl++)
#pragma unroll
            for (int ntl = 0; ntl < 4; ntl++) {
                acc2[ftl][ntl][0] = bias2v[ftl].x; acc2[ftl][ntl][1] = bias2v[ftl].y;
                acc2[ftl][ntl][2] = bias2v[ftl].z; acc2[ftl][ntl][3] = bias2v[ftl].w;
            }
#pragma unroll
        for (int ntl = 0; ntl < 4; ntl++)
#pragma unroll
            for (int kc = 0; kc < 4; kc++) {
                acc2[0][ntl] = __builtin_amdgcn_mfma_f32_16x16x32_f16(aw2[0][kc], bz[ntl][kc], acc2[0][ntl], 0, 0, 0);
                acc2[1][ntl] = __builtin_amdgcn_mfma_f32_16x16x32_f16(aw2[1][kc], bz[ntl][kc], acc2[1][ntl], 0, 0, 0);
            }
        __syncthreads();                 // S4: all sZ reads complete
        // --- stage acc2 -> sZ row-major via b64 ---
#pragma unroll
        for (int ftl = 0; ftl < 2; ftl++) {
            int f = fbase + ftl * 16 + fq * 4;
#pragma unroll
            for (int ntl = 0; ntl < 4; ntl++) {
                int n = nbase + ntl * 16 + col;
                u32 lo = pkh(acc2[ftl][ntl][0], acc2[ftl][ntl][1]);
                u32 hi = pkh(acc2[ftl][ntl][2], acc2[ftl][ntl][3]);
                *(uint2*)&sZ[n * 136 + f] = make_uint2(lo, hi);
            }
        }
        __syncthreads();                 // S5
#pragma unroll
        for (int i = 0; i < 4; i++) {
            int c = t + 512 * i;
            int n = c >> 4, k8 = c & 15;
            if (n < nvalid)
                *(uint4*)&out[((size_t)(base + n)) * HD + k8 * 8] =
                    *(const uint4*)&sZ[n * 136 + k8 * 8];
        }
    }
}

// ---------------- per-graph sum pool (f16 in, fp32 atomics out) ----------------
__global__ __launch_bounds__(64) void pool_kernel(const u16* __restrict__ h,
                                                  const int* __restrict__ gid,
                                                  float* __restrict__ out, int N) {
    const int CH = 32;
    int j = threadIdx.x;
    int start = blockIdx.x * CH;
    if (start >= N) return;
    int end = min(start + CH, N);
    int cur = gid[start];
    float x0 = 0.f, x1 = 0.f;
    for (int n = start; n < end; n++) {
        int g = gid[n];
        if (g != cur) {
            atomicAdd(&out[(size_t)cur * HD + 2 * j], x0);
            atomicAdd(&out[(size_t)cur * HD + 2 * j + 1], x1);
            cur = g; x0 = 0.f; x1 = 0.f;
        }
        u32 v = *(const u32*)&h[(size_t)n * HD + j * 2];
        x0 += hLo(v); x1 += hHi(v);
    }
    atomicAdd(&out[(size_t)cur * HD + 2 * j], x0);
    atomicAdd(&out[(size_t)cur * HD + 2 * j + 1], x1);
}

extern "C" void kernel_launch(void* const* d_in, const int* in_sizes, int n_in,
                              void* d_out, int out_size, void* d_ws, size_t ws_size,
                              hipStream_t stream) {
    (void)n_in; (void)ws_size;
    const float* x   = (const float*)d_in[0];
    const float* Wfc = (const float*)d_in[1];
    const float* bfc = (const float*)d_in[2];
    const float* W1  = (const float*)d_in[3];
    const float* b1  = (const float*)d_in[4];
    const float* W2  = (const float*)d_in[5];
    const float* b2  = (const float*)d_in[6];
    const int* src   = (const int*)d_in[7];
    const int* dst   = (const int*)d_in[8];
    const int* gid   = (const int*)d_in[9];

    int N = in_sizes[0] / DIN;       // 100000
    int E = in_sizes[7];             // 1600000
    int nTiles = (N + 127) / 128;
    int nB = (E + EB - 1) / EB;      // partition blocks (196)
    int nScan2 = NBKT * nB;          // histT length
    int nb2 = (nScan2 + 1023) / 1024;

    // workspace layout (~65 MB)
    u16* h = (u16*)d_ws;                          // N*128 f16
    u16* z = h + (size_t)N * HD;                  // N*128 f16
    int* off    = (int*)(z + (size_t)N * HD);     // N+1
    int* esrc   = off + (N + 1);                  // E
    int* bsums2 = esrc + E;                       // 256
    int* histT  = bsums2 + 256;                   // NBKT*nB
    u32* bpairs = (u32*)(histT + nScan2);         // E packed pairs

    // --- radix partition of edges by dst>>8 (no global atomics) ---
    rhist_kernel<<<nB, 256, 0, stream>>>(dst, histT, E, nB);
    scan1_kernel<<<nb2, 256, 0, stream>>>(histT, bsums2, nScan2);
    scan2_kernel<<<1, 1024, 0, stream>>>(bsums2, nb2);
    scan3_kernel<<<(nScan2 + 255) / 256, 256, 0, stream>>>(histT, bsums2, nScan2);
    rpos_kernel<<<nB, 256, 0, stream>>>(src, dst, histT, bpairs, E, nB);

    // --- fused per-node CSR offsets + scatter (per-bucket, LDS only) ---
    bfinal_kernel<<<NBKT, 256, 0, stream>>>(bpairs, histT, off, esrc, N, nB);

    // --- node projection (f16 out) ---
    fc_kernel<<<512, 512, 0, stream>>>(x, Wfc, bfc, h, N, nTiles);

    // --- 3x GINConv (standalone agg for max wave-parallelism + R8 MLP pair) ---
    for (int l = 0; l < 3; l++) {
        agg_kernel<<<(N + 3) / 4, 256, 0, stream>>>(h, off, esrc, z, N);
        mlp_pair_kernel<<<256, 512, 0, stream>>>(z, W1 + (size_t)l * HD * HD,
                                                 b1 + (size_t)l * HD,
                                                 W2 + (size_t)l * HD * HD,
                                                 b2 + (size_t)l * HD, h, N, nTiles);
    }

    // --- per-graph sum pooling ---
    zero_f32_kernel<<<(out_size + 255) / 256, 256, 0, stream>>>((float*)d_out, out_size);
    pool_kernel<<<(N + 31) / 32, 64, 0, stream>>>(h, gid, (float*)d_out, N);
}

// Round 3
// 430.734 us; speedup vs baseline: 1.0914x; 1.0154x over previous
//
#include <hip/hip_runtime.h>

#define DIN 55
#define HD 128
#define EB 8192          // edges per partition block
#define NBKT 512         // radix buckets (dst >> 8)

typedef unsigned short u16;
typedef unsigned int u32;
typedef short short8 __attribute__((ext_vector_type(8)));
typedef _Float16 h8 __attribute__((ext_vector_type(8)));
typedef float f32x4 __attribute__((ext_vector_type(4)));

// ---- fp16 helpers ----
// pack two f32 -> packed f16 pair (single v_cvt_pkrtz_f16_f32)
__device__ __forceinline__ u32 pkh(float a, float b) {
    auto r = __builtin_amdgcn_cvt_pkrtz(a, b);
    union { decltype(r) h; u32 u; } c; c.h = r; return c.u;
}
__device__ __forceinline__ float hLo(u32 u) {
    union { u16 s; _Float16 f; } c; c.s = (u16)u; return (float)c.f;
}
__device__ __forceinline__ float hHi(u32 u) {
    union { u16 s; _Float16 f; } c; c.s = (u16)(u >> 16); return (float)c.f;
}

// ---------------- utility ----------------
__global__ void zero_f32_kernel(float* p, int n) {
    int i = blockIdx.x * blockDim.x + threadIdx.x;
    if (i < n) p[i] = 0.f;
}

// ---------------- hierarchical inclusive scan (for histT only) ----------------
__global__ __launch_bounds__(256) void scan1_kernel(int* data, int* bsums, int n) {
    __shared__ int sT[256];
    int t = threadIdx.x;
    int base = blockIdx.x * 1024 + t * 4;
    int v0 = (base + 0 < n) ? data[base + 0] : 0;
    int v1 = (base + 1 < n) ? data[base + 1] : 0;
    int v2 = (base + 2 < n) ? data[base + 2] : 0;
    int v3 = (base + 3 < n) ? data[base + 3] : 0;
    v1 += v0; v2 += v1; v3 += v2;
    sT[t] = v3;
    __syncthreads();
    for (int off = 1; off < 256; off <<= 1) {
        int x = (t >= off) ? sT[t - off] : 0;
        __syncthreads();
        sT[t] += x;
        __syncthreads();
    }
    int excl = (t == 0) ? 0 : sT[t - 1];
    if (base + 0 < n) data[base + 0] = v0 + excl;
    if (base + 1 < n) data[base + 1] = v1 + excl;
    if (base + 2 < n) data[base + 2] = v2 + excl;
    if (base + 3 < n) data[base + 3] = v3 + excl;
    if (t == 255) bsums[blockIdx.x] = sT[255];
}
__global__ __launch_bounds__(1024) void scan2_kernel(int* bsums, int nb) {
    __shared__ int s[1024];
    int t = threadIdx.x;
    int v = (t < nb) ? bsums[t] : 0;
    s[t] = v;
    __syncthreads();
    for (int o = 1; o < 1024; o <<= 1) {
        int x = (t >= o) ? s[t - o] : 0;
        __syncthreads();
        s[t] += x;
        __syncthreads();
    }
    if (t < nb) bsums[t] = s[t] - v;   // exclusive
}
__global__ void scan3_kernel(int* data, const int* __restrict__ bsums, int n) {
    int i = blockIdx.x * blockDim.x + threadIdx.x;
    if (i < n) data[i] += bsums[i >> 10];
}

// ---------------- radix partition of edges by dst>>8 ----------------
__global__ __launch_bounds__(256) void rhist_kernel(const int* __restrict__ dst,
                                                    int* __restrict__ histT, int E, int nB) {
    __shared__ int hh[NBKT];
    int t = threadIdx.x;
    for (int i = t; i < NBKT; i += 256) hh[i] = 0;
    __syncthreads();
    int base = blockIdx.x * EB;
    int end = min(base + EB, E);
    for (int i = base + t; i < end; i += 256) atomicAdd(&hh[dst[i] >> 8], 1);
    __syncthreads();
    for (int b = t; b < NBKT; b += 256) histT[b * nB + blockIdx.x] = hh[b];
}

// ticket from scanned histT directly (exclusive base = scanned[flat-1]); LDS atomics only
__global__ __launch_bounds__(256) void rpos_kernel(const int* __restrict__ src,
                                                   const int* __restrict__ dst,
                                                   const int* __restrict__ scanned,
                                                   u32* __restrict__ bpairs, int E, int nB) {
    __shared__ int cur[NBKT];
    int t = threadIdx.x;
    for (int b = t; b < NBKT; b += 256) {
        int idx = b * nB + blockIdx.x;
        cur[b] = (idx == 0) ? 0 : scanned[idx - 1];
    }
    __syncthreads();
    int base = blockIdx.x * EB;
    int end = min(base + EB, E);
    for (int i = base + t; i < end; i += 256) {
        int d = dst[i];
        int p = atomicAdd(&cur[d >> 8], 1);
        bpairs[p] = ((u32)src[i] << 8) | (u32)(d & 255);
    }
}

// fused per-bucket: count -> local scan -> write off -> scatter esrc (all LDS)
__global__ __launch_bounds__(256) void bfinal_kernel(const u32* __restrict__ bpairs,
                                                     const int* __restrict__ scanned,
                                                     int* __restrict__ off,
                                                     int* __restrict__ esrc, int N, int nB) {
    __shared__ int cnt[256];
    __shared__ int sc[256];
    __shared__ int cur[256];
    int b = blockIdx.x, t = threadIdx.x;
    int lo = (b == 0) ? 0 : scanned[b * nB - 1];
    int hi = scanned[(b + 1) * nB - 1];
    cnt[t] = 0;
    __syncthreads();
    for (int i = lo + t; i < hi; i += 256) atomicAdd(&cnt[bpairs[i] & 255u], 1);
    __syncthreads();
    int v = cnt[t];
    sc[t] = v;
    __syncthreads();
    for (int o = 1; o < 256; o <<= 1) {
        int x = (t >= o) ? sc[t - o] : 0;
        __syncthreads();
        sc[t] += x;
        __syncthreads();
    }
    int incl = sc[t];
    int gbase = lo + incl - v;
    int n = b * 256 + t;
    if (n < N) off[n] = gbase;
    if (n == N - 1) off[N] = lo + incl;
    cur[t] = gbase;
    __syncthreads();
    for (int i = lo + t; i < hi; i += 256) {
        u32 p = bpairs[i];
        int q = atomicAdd(&cur[p & 255u], 1);
        esrc[q] = (int)(p >> 8);
    }
}

// ---------------- node projection: h = x @ W_fc + b_fc  (fp32 math, f16 out) ----------------
__global__ __launch_bounds__(512, 2) void fc_kernel(const float* __restrict__ x,
                                                    const float* __restrict__ Wfc,
                                                    const float* __restrict__ bfc,
                                                    u16* __restrict__ h,
                                                    int N, int nTiles) {
    __shared__ float sW[DIN * HD];
    __shared__ float sX[128 * 56];
    for (int i = threadIdx.x; i < DIN * HD / 4; i += 512)
        ((float4*)sW)[i] = ((const float4*)Wfc)[i];
    const int c = threadIdx.x & 15;
    const int r = threadIdx.x >> 4;
    float4 bb0 = ((const float4*)bfc)[2 * c];
    float4 bb1 = ((const float4*)bfc)[2 * c + 1];

    for (int tile = blockIdx.x; tile < nTiles; tile += gridDim.x) {
        int base = tile * 128;
        int limit = min(128, N - base) * DIN;
        __syncthreads();
        for (int i = threadIdx.x; i < 128 * DIN; i += 512) {
            float v = (i < limit) ? x[(size_t)base * DIN + i] : 0.f;
            sX[(i / DIN) * 56 + (i % DIN)] = v;
        }
        __syncthreads();

        float acc[4][8];
#pragma unroll
        for (int ii = 0; ii < 4; ii++) {
            acc[ii][0] = bb0.x; acc[ii][1] = bb0.y; acc[ii][2] = bb0.z; acc[ii][3] = bb0.w;
            acc[ii][4] = bb1.x; acc[ii][5] = bb1.y; acc[ii][6] = bb1.z; acc[ii][7] = bb1.w;
        }
        const int n0 = r * 4;
#pragma unroll 5
        for (int k = 0; k < DIN; k++) {
            float4 w0 = *(const float4*)&sW[k * HD + c * 8];
            float4 w1 = *(const float4*)&sW[k * HD + c * 8 + 4];
            float av[4] = {sX[(n0 + 0) * 56 + k], sX[(n0 + 1) * 56 + k],
                           sX[(n0 + 2) * 56 + k], sX[(n0 + 3) * 56 + k]};
#pragma unroll
            for (int ii = 0; ii < 4; ii++) {
                acc[ii][0] += av[ii] * w0.x; acc[ii][1] += av[ii] * w0.y;
                acc[ii][2] += av[ii] * w0.z; acc[ii][3] += av[ii] * w0.w;
                acc[ii][4] += av[ii] * w1.x; acc[ii][5] += av[ii] * w1.y;
                acc[ii][6] += av[ii] * w1.z; acc[ii][7] += av[ii] * w1.w;
            }
        }
        int nvalid = N - base;
#pragma unroll
        for (int ii = 0; ii < 4; ii++) {
            if (n0 + ii < nvalid) {
                u32 p0 = pkh(acc[ii][0], acc[ii][1]);
                u32 p1 = pkh(acc[ii][2], acc[ii][3]);
                u32 p2 = pkh(acc[ii][4], acc[ii][5]);
                u32 p3 = pkh(acc[ii][6], acc[ii][7]);
                *(uint4*)&h[(size_t)(base + n0 + ii) * HD + c * 8] = make_uint4(p0, p1, p2, p3);
            }
        }
    }
}

// ---------------- edge aggregation: z[n] = h[n] + sum_{e} h[esrc[e]]  (f16) ----------------
// one 16-lane QUARTER per node: lane q owns feature chunk [q*8, q*8+8). 4 independent
// accumulator slots -> 4 edges in flight per quarter = 16 row-gathers in flight per wave
// (4x the per-wave MLP of the old wave-per-node scheme), and the cross-lane shuffle
// reduction disappears entirely (combine in-register, all 16 lanes store 16B coalesced).
__global__ __launch_bounds__(256) void agg_kernel(const u16* __restrict__ h,
                                                  const int* __restrict__ off,
                                                  const int* __restrict__ esrc,
                                                  u16* __restrict__ z, int N) {
    int t = threadIdx.x;
    int q = t & 15;                        // feature chunk within row
    int n = blockIdx.x * 16 + (t >> 4);    // node handled by this quarter
    if (n >= N) return;
    int s0 = off[n], s1 = off[n + 1];
    const size_t qo = (size_t)q * 8;
    h8 a0 = {0, 0, 0, 0, 0, 0, 0, 0};
    h8 a1 = a0, a2 = a0, a3 = a0;
    int i = s0;
    for (; i + 4 <= s1; i += 4) {
        int e0 = esrc[i + 0], e1 = esrc[i + 1];
        int e2 = esrc[i + 2], e3 = esrc[i + 3];
        a0 += *(const h8*)&h[(size_t)e0 * HD + qo];
        a1 += *(const h8*)&h[(size_t)e1 * HD + qo];
        a2 += *(const h8*)&h[(size_t)e2 * HD + qo];
        a3 += *(const h8*)&h[(size_t)e3 * HD + qo];
    }
    if (i + 2 <= s1) {
        int e0 = esrc[i], e1 = esrc[i + 1];
        a0 += *(const h8*)&h[(size_t)e0 * HD + qo];
        a1 += *(const h8*)&h[(size_t)e1 * HD + qo];
        i += 2;
    }
    if (i < s1) {
        int e0 = esrc[i];
        a2 += *(const h8*)&h[(size_t)e0 * HD + qo];
    }
    a3 += *(const h8*)&h[(size_t)n * HD + qo];     // self term: (1+eps)*h, eps=0
    h8 s = (a0 + a1) + (a2 + a3);
    union { h8 v; uint4 u; } A; A.v = s;
    *(uint4*)&z[(size_t)n * HD + qo] = A.u;
}

// ---------------- fused MLP pair (R8 structure, f16 MFMA): ----------------
// Transposed GEMMs (A = weights, B = activations). Coalesced prefetch staging through sA,
// z1 via b64 row-major LDS, GEMM2 B-frags contiguous b128, coalesced epilogue through sZ.
__global__ __launch_bounds__(512, 2) void mlp_pair_kernel(const u16* __restrict__ in,
                                                          const float* __restrict__ W1,
                                                          const float* __restrict__ b1,
                                                          const float* __restrict__ W2,
                                                          const float* __restrict__ b2,
                                                          u16* __restrict__ out,
                                                          int N, int nTiles) {
    __shared__ u16 sB1[16384];           // W1 frags: [ft][kc][slot][8]
    __shared__ u16 sB2[16384];           // W2 frags
    __shared__ u16 sA[16384];            // activation frags: [nt][kc][slot][8]
    __shared__ u16 sZ[128 * 136];        // row-major activations [node][feature], pad 136

    const int t = threadIdx.x;
    // --- build weight frags (stage fp32->f16 rows into sZ scratch, then fragment) ---
    for (int wsel = 0; wsel < 2; wsel++) {
        const float* W = wsel ? W2 : W1;
        u16* sB = wsel ? sB2 : sB1;
        __syncthreads();
        for (int c = t; c < 128 * 32; c += 512) {
            int k = c >> 5, j4 = c & 31;
            float4 wv = ((const float4*)W)[c];
            u32 p0 = pkh(wv.x, wv.y);
            u32 p1 = pkh(wv.z, wv.w);
            *(uint2*)&sZ[k * 136 + j4 * 4] = make_uint2(p0, p1);
        }
        __syncthreads();
        for (int e = t; e < 2048; e += 512) {
            int L = e & 63, gq = e >> 6;
            int ct = gq >> 2, kc = gq & 3;
            int j = ct * 16 + (L & 15);
            int k0 = kc * 32 + ((L >> 4) << 3);
            short8 sv;
#pragma unroll
            for (int i = 0; i < 8; i++) sv[i] = (short)sZ[(k0 + i) * 136 + j];
            int slot = L ^ (kc << 1);
            *(short8*)&sB[(((ct << 2) + kc) << 6 | slot) * 8] = sv;
        }
    }

    const int w = t >> 6, lane = t & 63;
    const int col = lane & 15;           // node within tile
    const int fq = lane >> 4;            // feature quad
    const int fbase = (w & 3) << 5;      // wave's 32 features (2 f-tiles)
    const int nbase = (w >> 2) << 6;     // wave's 64 nodes (4 n-tiles)
    float4 bias1v[2], bias2v[2];
#pragma unroll
    for (int ftl = 0; ftl < 2; ftl++) {
        bias1v[ftl] = *(const float4*)&b1[fbase + ftl * 16 + fq * 4];
        bias2v[ftl] = *(const float4*)&b2[fbase + ftl * 16 + fq * 4];
    }

    // prefetch tile 0
    uint4 pf[4];
    int tile = blockIdx.x;
    if (tile < nTiles) {
        int base = tile * 128;
        int limit = min(128, N - base) * 16;
#pragma unroll
        for (int i = 0; i < 4; i++) {
            int c = t + 512 * i;
            uint4 raw = make_uint4(0, 0, 0, 0);
            if (c < limit)
                raw = *(const uint4*)&in[((size_t)(base + (c >> 4))) * HD + (c & 15) * 8];
            pf[i] = raw;
        }
    }

    for (; tile < nTiles; tile += gridDim.x) {
        int base = tile * 128;
        int nvalid = N - base;
        __syncthreads();                 // S1: prev tile fully done (sA & sZ free)
#pragma unroll
        for (int i = 0; i < 4; i++) {    // regs -> sA (swizzled fragment slots)
            int c = t + 512 * i;
            int n = c >> 4, k8 = c & 15;
            int nt = n >> 4, kc = k8 >> 2;
            int L = ((k8 & 3) << 4) | (n & 15);
            int slot = L ^ (kc << 1);
            *(uint4*)&sA[(((nt << 2) + kc) << 6 | slot) * 8] = pf[i];
        }
        __syncthreads();                 // S2

        // issue next tile's prefetch (overlaps with both GEMMs)
        int ntile = tile + gridDim.x;
        if (ntile < nTiles) {
            int nb2 = ntile * 128;
            int nlimit = min(128, N - nb2) * 16;
#pragma unroll
            for (int i = 0; i < 4; i++) {
                int c = t + 512 * i;
                uint4 raw = make_uint4(0, 0, 0, 0);
                if (c < nlimit)
                    raw = *(const uint4*)&in[((size_t)(nb2 + (c >> 4))) * HD + (c & 15) * 8];
                pf[i] = raw;
            }
        }

        // --- GEMM1: D[feature][node] = W1^T (A) x in^T (B) ---
        h8 aw1[2][4];
#pragma unroll
        for (int ftl = 0; ftl < 2; ftl++) {
            int ft = ((w & 3) << 1) + ftl;
#pragma unroll
            for (int kc = 0; kc < 4; kc++)
                aw1[ftl][kc] = *(const h8*)&sB1[(((ft << 2) + kc) << 6 | (lane ^ (kc << 1))) * 8];
        }
        h8 bx[4][4];
#pragma unroll
        for (int ntl = 0; ntl < 4; ntl++) {
            int nt = ((w >> 2) << 2) + ntl;
#pragma unroll
            for (int kc = 0; kc < 4; kc++)
                bx[ntl][kc] = *(const h8*)&sA[(((nt << 2) + kc) << 6 | (lane ^ (kc << 1))) * 8];
        }
        f32x4 acc1[2][4];
#pragma unroll
        for (int ftl = 0; ftl < 2; ftl++)
#pragma unroll
            for (int ntl = 0; ntl < 4; ntl++) {
                acc1[ftl][ntl][0] = bias1v[ftl].x; acc1[ftl][ntl][1] = bias1v[ftl].y;
                acc1[ftl][ntl][2] = bias1v[ftl].z; acc1[ftl][ntl][3] = bias1v[ftl].w;
            }
#pragma unroll
        for (int ntl = 0; ntl < 4; ntl++)
#pragma unroll
            for (int kc = 0; kc < 4; kc++) {
                acc1[0][ntl] = __builtin_amdgcn_mfma_f32_16x16x32_f16(aw1[0][kc], bx[ntl][kc], acc1[0][ntl], 0, 0, 0);
                acc1[1][ntl] = __builtin_amdgcn_mfma_f32_16x16x32_f16(aw1[1][kc], bx[ntl][kc], acc1[1][ntl], 0, 0, 0);
            }
        // --- write z1 = relu(acc1) row-major into sZ via b64 (4 consecutive features) ---
#pragma unroll
        for (int ftl = 0; ftl < 2; ftl++) {
            int f = fbase + ftl * 16 + fq * 4;
#pragma unroll
            for (int ntl = 0; ntl < 4; ntl++) {
                int n = nbase + ntl * 16 + col;
                float v0 = fmaxf(acc1[ftl][ntl][0], 0.f);
                float v1 = fmaxf(acc1[ftl][ntl][1], 0.f);
                float v2 = fmaxf(acc1[ftl][ntl][2], 0.f);
                float v3 = fmaxf(acc1[ftl][ntl][3], 0.f);
                u32 lo = pkh(v0, v1);
                u32 hi = pkh(v2, v3);
                *(uint2*)&sZ[n * 136 + f] = make_uint2(lo, hi);
            }
        }
        __syncthreads();                 // S3: z1 ready
        // --- GEMM2: D[feature][node] = W2^T (A) x z1^T (B); B-frags contiguous b128 ---
        h8 aw2[2][4];
#pragma unroll
        for (int ftl = 0; ftl < 2; ftl++) {
            int ft = ((w & 3) << 1) + ftl;
#pragma unroll
            for (int kc = 0; kc < 4; kc++)
                aw2[ftl][kc] = *(const h8*)&sB2[(((ft << 2) + kc) << 6 | (lane ^ (kc << 1))) * 8];
        }
        h8 bz[4][4];
#pragma unroll
        for (int ntl = 0; ntl < 4; ntl++) {
            int n = nbase + ntl * 16 + col;
#pragma unroll
            for (int kc = 0; kc < 4; kc++) {
                int k0 = kc * 32 + fq * 8;
                bz[ntl][kc] = *(const h8*)&sZ[n * 136 + k0];
            }
        }
        f32x4 acc2[2][4];
#pragma unroll
        for (int ftl = 0; ftl < 2; ftl++)
#pragma unroll
            for (int ntl = 0; ntl < 4; ntl++) {
                acc2[ftl][ntl][0] = bias2v[ftl].x; acc2[ftl][ntl][1] = bias2v[ftl].y;
                acc2[ftl][ntl][2] = bias2v[ftl].z; acc2[ftl][ntl][3] = bias2v[ftl].w;
            }
#pragma unroll
        for (int ntl = 0; ntl < 4; ntl++)
#pragma unroll
            for (int kc = 0; kc < 4; kc++) {
                acc2[0][ntl] = __builtin_amdgcn_mfma_f32_16x16x32_f16(aw2[0][kc], bz[ntl][kc], acc2[0][ntl], 0, 0, 0);
                acc2[1][ntl] = __builtin_amdgcn_mfma_f32_16x16x32_f16(aw2[1][kc], bz[ntl][kc], acc2[1][ntl], 0, 0, 0);
            }
        __syncthreads();                 // S4: all sZ reads complete
        // --- stage acc2 -> sZ row-major via b64 ---
#pragma unroll
        for (int ftl = 0; ftl < 2; ftl++) {
            int f = fbase + ftl * 16 + fq * 4;
#pragma unroll
            for (int ntl = 0; ntl < 4; ntl++) {
                int n = nbase + ntl * 16 + col;
                u32 lo = pkh(acc2[ftl][ntl][0], acc2[ftl][ntl][1]);
                u32 hi = pkh(acc2[ftl][ntl][2], acc2[ftl][ntl][3]);
                *(uint2*)&sZ[n * 136 + f] = make_uint2(lo, hi);
            }
        }
        __syncthreads();                 // S5
#pragma unroll
        for (int i = 0; i < 4; i++) {
            int c = t + 512 * i;
            int n = c >> 4, k8 = c & 15;
            if (n < nvalid)
                *(uint4*)&out[((size_t)(base + n)) * HD + k8 * 8] =
                    *(const uint4*)&sZ[n * 136 + k8 * 8];
        }
    }
}

// ---------------- per-graph sum pool (f16 in, fp32 atomics out) ----------------
__global__ __launch_bounds__(64) void pool_kernel(const u16* __restrict__ h,
                                                  const int* __restrict__ gid,
                                                  float* __restrict__ out, int N) {
    const int CH = 32;
    int j = threadIdx.x;
    int start = blockIdx.x * CH;
    if (start >= N) return;
    int end = min(start + CH, N);
    int cur = gid[start];
    float x0 = 0.f, x1 = 0.f;
    for (int n = start; n < end; n++) {
        int g = gid[n];
        if (g != cur) {
            atomicAdd(&out[(size_t)cur * HD + 2 * j], x0);
            atomicAdd(&out[(size_t)cur * HD + 2 * j + 1], x1);
            cur = g; x0 = 0.f; x1 = 0.f;
        }
        u32 v = *(const u32*)&h[(size_t)n * HD + j * 2];
        x0 += hLo(v); x1 += hHi(v);
    }
    atomicAdd(&out[(size_t)cur * HD + 2 * j], x0);
    atomicAdd(&out[(size_t)cur * HD + 2 * j + 1], x1);
}

extern "C" void kernel_launch(void* const* d_in, const int* in_sizes, int n_in,
                              void* d_out, int out_size, void* d_ws, size_t ws_size,
                              hipStream_t stream) {
    (void)n_in; (void)ws_size;
    const float* x   = (const float*)d_in[0];
    const float* Wfc = (const float*)d_in[1];
    const float* bfc = (const float*)d_in[2];
    const float* W1  = (const float*)d_in[3];
    const float* b1  = (const float*)d_in[4];
    const float* W2  = (const float*)d_in[5];
    const float* b2  = (const float*)d_in[6];
    const int* src   = (const int*)d_in[7];
    const int* dst   = (const int*)d_in[8];
    const int* gid   = (const int*)d_in[9];

    int N = in_sizes[0] / DIN;       // 100000
    int E = in_sizes[7];             // 1600000
    int nTiles = (N + 127) / 128;
    int nB = (E + EB - 1) / EB;      // partition blocks (196)
    int nScan2 = NBKT * nB;          // histT length
    int nb2 = (nScan2 + 1023) / 1024;

    // workspace layout (~65 MB)
    u16* h = (u16*)d_ws;                          // N*128 f16
    u16* z = h + (size_t)N * HD;                  // N*128 f16
    int* off    = (int*)(z + (size_t)N * HD);     // N+1
    int* esrc   = off + (N + 1);                  // E
    int* bsums2 = esrc + E;                       // 256
    int* histT  = bsums2 + 256;                   // NBKT*nB
    u32* bpairs = (u32*)(histT + nScan2);         // E packed pairs

    // --- radix partition of edges by dst>>8 (no global atomics) ---
    rhist_kernel<<<nB, 256, 0, stream>>>(dst, histT, E, nB);
    scan1_kernel<<<nb2, 256, 0, stream>>>(histT, bsums2, nScan2);
    scan2_kernel<<<1, 1024, 0, stream>>>(bsums2, nb2);
    scan3_kernel<<<(nScan2 + 255) / 256, 256, 0, stream>>>(histT, bsums2, nScan2);
    rpos_kernel<<<nB, 256, 0, stream>>>(src, dst, histT, bpairs, E, nB);

    // --- fused per-node CSR offsets + scatter (per-bucket, LDS only) ---
    bfinal_kernel<<<NBKT, 256, 0, stream>>>(bpairs, histT, off, esrc, N, nB);

    // --- node projection (f16 out) ---
    fc_kernel<<<512, 512, 0, stream>>>(x, Wfc, bfc, h, N, nTiles);

    // --- 3x GINConv (quarter-wave agg + R8 MLP pair) ---
    for (int l = 0; l < 3; l++) {
        agg_kernel<<<(N + 15) / 16, 256, 0, stream>>>(h, off, esrc, z, N);
        mlp_pair_kernel<<<256, 512, 0, stream>>>(z, W1 + (size_t)l * HD * HD,
                                                 b1 + (size_t)l * HD,
                                                 W2 + (size_t)l * HD * HD,
                                                 b2 + (size_t)l * HD, h, N, nTiles);
    }

    // --- per-graph sum pooling ---
    zero_f32_kernel<<<(out_size + 255) / 256, 256, 0, stream>>>((float*)d_out, out_size);
    pool_kernel<<<(N + 31) / 32, 64, 0, stream>>>(h, gid, (float*)d_out, N);
}